// Round 9
// baseline (196.122 us; speedup 1.0000x reference)
//
#include <hip/hip_runtime.h>

#define NA 384
#define NB 384
#define NBATCH 64
#define NEGV -1e20f
#define C 8            // steps per chunk
#define TOT_CH 54      // s0 = 1+8k, k=0..53 (lane47 needs s up to 431)
#define RPW 48         // rows per relay wave
#define NBLK 4         // blocks (quadrants) per batch
#define WPITCH 68      // wtile row pitch (floats)
#define LOG2E 1.44269504088896340736f
#define LN2   0.69314718055994530942f
#define MUP (NB + 1)

typedef float f4 __attribute__((ext_vector_type(4)));
typedef unsigned long long u64;

struct alignas(16) SharedT {
    float stage[2][2][RPW * 9];     // [ring][relay][lane*9+c] mu' staging
    float wtile[4][2][6 * WPITCH];  // transposed W ring, 4 deep
    float bound[NB + 1];            // intra-block edge row (log2 domain)
    int   progress;                 // intra edge: max col published by RA
    int   computed[2];
    int   drained[2][2];
    int   wready[2];
};

// Skewed-coalesced W load: instr i covers local rows 8i..8i+7 x 8 consecutive
// cols (8 cache lines/instr). lane l -> local row 8i+(l>>3),
// col = 8kk + (l&7) - row (clamped; clamped values unused by guarded relay).
__device__ __forceinline__ void loadW6(const float* __restrict__ Wb, int wrow0,
                                       int kk, int l, float (&r)[6])
{
    const int rl = l >> 3, cc = l & 7;
    const int colb = 8 * kk + cc;
#pragma unroll
    for (int i = 0; i < 6; ++i) {
        const int row = 8 * i + rl;
        int col = colb - row;
        col = col < 0 ? 0 : (col > NB - 1 ? NB - 1 : col);
        r[i] = Wb[(size_t)(wrow0 + row) * NB + col];
    }
}

__device__ __forceinline__ void writeWt6(float* __restrict__ wt,
                                         const float (&r)[6], int l) {
#pragma unroll
    for (int i = 0; i < 6; ++i) wt[i * WPITCH + l] = r[i];
}

// lane l's 8 consecutive W values for a chunk, premultiplied by LOG2E
__device__ __forceinline__ void readWc(const float* __restrict__ wt, int l,
                                       float (&wc)[8]) {
    const int ll = l < RPW ? l : RPW - 1;          // clamp idle lanes
    const int wb = (ll >> 3) * WPITCH + (ll & 7) * 8;
    const f4 lo = *(const f4*)(wt + wb);
    const f4 hi = *(const f4*)(wt + wb + 4);
    wc[0] = lo.x * LOG2E; wc[1] = lo.y * LOG2E;
    wc[2] = lo.z * LOG2E; wc[3] = lo.w * LOG2E;
    wc[4] = hi.x * LOG2E; wc[5] = hi.y * LOG2E;
    wc[6] = hi.z * LOG2E; wc[7] = hi.w * LOG2E;
}

__device__ __forceinline__ u64 packbv(int j, float v) {
    return ((u64)(unsigned)j << 32) | (u64)__float_as_uint(v);
}

// EIN/EOUT: 0 = none, 1 = LDS (intra-block), 2 = global (inter-block)
template<int EIN, int EOUT, bool FULL>
__device__ __forceinline__ void chunk_body(int k, int r, int l,
        float (&wc)[8], float (&bnd)[8], u64 (&pkN)[8],
        float& val, float& diag, SharedT& sh,
        u64* __restrict__ gOut, const u64* __restrict__ gIn)
{
    const int s0 = 1 + k * C;
    float* st = &sh.stage[k & 1][r][0];

    // ---- global edge in: verify prefetched payload, issue next ----
    if (EIN == 2) {
        bool ok;
        do {
            ok = true;
#pragma unroll
            for (int c = 0; c < C; ++c) {
                const int s = s0 + c;
                if (s <= NB) ok = ok && ((int)(pkN[c] >> 32) == s);
            }
            if (!ok) {
#pragma unroll
                for (int c = 0; c < C; ++c) {
                    const int s = s0 + c;
                    if (s <= NB)
                        pkN[c] = __hip_atomic_load(gIn + s, __ATOMIC_RELAXED,
                                                   __HIP_MEMORY_SCOPE_AGENT);
                }
            }
        } while (!ok);
#pragma unroll
        for (int c = 0; c < C; ++c) bnd[c] = __uint_as_float((unsigned)pkN[c]);
        if (k + 1 < TOT_CH && s0 + C <= NB) {      // next chunk needs boundary
#pragma unroll
            for (int c = 0; c < C; ++c) {
                const int s = s0 + C + c;
                if (s <= NB)
                    pkN[c] = __hip_atomic_load(gIn + s, __ATOMIC_RELAXED,
                                               __HIP_MEMORY_SCOPE_AGENT);
            }
        }
    }

    // ---- 8 relay steps ----
    __builtin_amdgcn_s_setprio(1);
#pragma unroll
    for (int c = 0; c < C; ++c) {
        const int s = s0 + c;
        float upv = __int_as_float(__builtin_amdgcn_update_dpp(
            0, __float_as_int(val), 0x138 /*WAVE_SHR1*/, 0xF, 0xF, false));
        if (l == 0) upv = (EIN != 0 && s <= NB) ? bnd[c] : NEGV;
        const int j = s - l;
        if ((FULL && l < RPW) || (!FULL && l < RPW && j >= 1 && j <= NB)) {
            const float m  = fmaxf(fmaxf(upv, val), diag);   // v_max3_f32
            const float eu = exp2f(upv  - m);
            const float el = exp2f(val  - m);
            const float ed = exp2f(diag - m);
            const float nv = wc[c] + m + __log2f(eu + el + ed);
            st[l * 9 + c] = nv;                              // ds_write_b32
            if (EOUT == 1 && l == RPW - 1) sh.bound[j] = nv;
            if (EOUT == 2 && l == RPW - 1)
                __hip_atomic_store(gOut + j, packbv(j, nv), __ATOMIC_RELAXED,
                                   __HIP_MEMORY_SCOPE_AGENT);
            diag = upv;
            val  = nv;
        }
    }
    asm volatile("s_waitcnt lgkmcnt(0)" ::: "memory");       // DS ops only
    if (l == RPW - 1) {
        if (EOUT == 1) {
            const int done = s0 + C - 1 - (RPW - 1);         // 8k - 39
            if (done >= 1) *(volatile int*)&sh.progress = done;
        }
        *(volatile int*)&sh.computed[r] = k + 1;
    }
    __builtin_amdgcn_s_setprio(0);

    // ---- end-of-chunk prefetches for k+1 (latencies overlap each other) ----
    if (k + 1 < TOT_CH) {
        volatile int* wr = &sh.wready[r];
        while (*wr < k + 2) { }
        __builtin_amdgcn_sched_barrier(0);
        asm volatile("" ::: "memory");
        readWc(&sh.wtile[(k + 1) & 3][r][0], l, wc);

        volatile int* dr = &sh.drained[r][(k + 1) & 1];
        while (*dr < k - 1) __builtin_amdgcn_s_sleep(1);
        __builtin_amdgcn_sched_barrier(0);
        asm volatile("" ::: "memory");

        if (EIN == 1 && s0 + C <= NB) {                      // k+1 <= 47
            int need = 8 * k + 16; need = need > NB ? NB : need;
            volatile int* pr = &sh.progress;
            while (*pr < need) { }
            __builtin_amdgcn_sched_barrier(0);
            asm volatile("" ::: "memory");
#pragma unroll
            for (int c = 0; c < C; ++c) {
                int s = s0 + C + c; s = s > NB ? NB : s;
                bnd[c] = sh.bound[s];
            }
        }
    }
}

template<int EIN, int EOUT>
__device__ __forceinline__ void relay_run(int r, int l, SharedT& sh, int rb48,
        u64* __restrict__ gOut, const u64* __restrict__ gIn)
{
    float val  = NEGV;                            // mu'[row][j-1]
    float diag = (rb48 + l == 0) ? 0.0f : NEGV;   // mu'[row-1][0]
    float wc[8], bnd[8];
    u64 pkN[8];

    {   // W prologue
        volatile int* wr = &sh.wready[r];
        while (*wr < 1) { }
        __builtin_amdgcn_sched_barrier(0);
        asm volatile("" ::: "memory");
        readWc(&sh.wtile[0][r][0], l, wc);
    }
    if (EIN == 1) {   // boundary prologue (chunk 0: cols 1..8)
        volatile int* pr = &sh.progress;
        while (*pr < C) { }
        __builtin_amdgcn_sched_barrier(0);
        asm volatile("" ::: "memory");
#pragma unroll
        for (int c = 0; c < C; ++c) bnd[c] = sh.bound[1 + c];
    }
    if (EIN == 2) {   // issue loads; chunk 0 body verifies
#pragma unroll
        for (int c = 0; c < C; ++c)
            pkN[c] = __hip_atomic_load(gIn + 1 + c, __ATOMIC_RELAXED,
                                       __HIP_MEMORY_SCOPE_AGENT);
    }

    for (int k = 0; k < 6; ++k)
        chunk_body<EIN, EOUT, false>(k, r, l, wc, bnd, pkN, val, diag, sh, gOut, gIn);
    for (int k = 6; k < 48; ++k)
        chunk_body<EIN, EOUT, true >(k, r, l, wc, bnd, pkN, val, diag, sh, gOut, gIn);
    for (int k = 48; k < TOT_CH; ++k)
        chunk_body<EIN, EOUT, false>(k, r, l, wc, bnd, pkN, val, diag, sh, gOut, gIn);
}

template<bool FULL>
__device__ __forceinline__ void io_iter(int k, int r, int l,
        const float* __restrict__ Wb, int rb48, float* __restrict__ mub,
        float (&wreg)[6], SharedT& sh)
{
    volatile int* cp = &sh.computed[r];
    while (*cp < k + 1) __builtin_amdgcn_s_sleep(1);
    __builtin_amdgcn_sched_barrier(0);
    asm volatile("" ::: "memory");

    // stage -> regs (transposed), release ring slot immediately
    const float* st = &sh.stage[k & 1][r][0];
    const int lr = l >> 3, cc = l & 7;
    float v[6];
#pragma unroll
    for (int qq = 0; qq < 6; ++qq) v[qq] = st[(lr + 8 * qq) * 9 + cc];
    asm volatile("s_waitcnt lgkmcnt(0)" ::: "memory");
    if (l == 0) *(volatile int*)&sh.drained[r][k & 1] = k;

    // W tile for chunk k+3 from a ~2-period-old register load (vmcnt free)
    if (k + 3 < TOT_CH) {
        writeWt6(&sh.wtile[(k + 3) & 3][r][0], wreg, l);
        asm volatile("s_waitcnt lgkmcnt(0)" ::: "memory");
        if (l == 0) *(volatile int*)&sh.wready[r] = k + 4;
        if (k + 5 < TOT_CH) loadW6(Wb, rb48, k + 5, l, wreg);
    }

    // mu stores LAST (fire-and-forget); 8 rows x 8 cols per wave instr
    const int colbase = k * C;
#pragma unroll
    for (int qq = 0; qq < 6; ++qq) {
        const int row = lr + 8 * qq;
        const int col = colbase + cc - row;
        if (FULL || (unsigned)col < (unsigned)NB)
            mub[(size_t)(rb48 + row + 1) * MUP + col + 1] = v[qq] * LN2;
    }
}

__global__ __launch_bounds__(256) void dtw_mu(const float* __restrict__ W,
                                              float* __restrict__ mu)
{
    __shared__ SharedT sh;
    const int bid = blockIdx.x;
    const int b = bid & 63, q = bid >> 6;          // same-b blocks -> same XCD
    const int tid = threadIdx.x;
    const int w = tid >> 6, l = tid & 63;

    const float* Wb = W + (size_t)b * NA * NB;
    float* mub = mu + (size_t)b * MUP * MUP;
    u64* edge = (u64*)(mu + (size_t)NBATCH * MUP * MUP) + (size_t)b * 3 * 400;

    if (q == 0)
        for (int t = tid; t < MUP; t += 256) mub[t] = (t == 0) ? 0.0f : NEGV;
    if (tid < 96) mub[(size_t)(96 * q + tid + 1) * MUP] = NEGV;   // col 0 span
    if (tid < 2) { sh.computed[tid] = 0; sh.wready[tid] = 0; }
    if (tid < 4) sh.drained[tid >> 1][tid & 1] = -1;
    if (tid == 0) sh.progress = 0;
    __syncthreads();

    if (w < 2) {
        // -------- relay waves: RA (w=0, rows 96q+1..+48), RB (w=1, +49..+96)
        const int r = w;
        const int rb48 = 96 * q + 48 * r;          // W row of lane 0
        if (r == 0) {
            if (q == 0) relay_run<0, 1>(r, l, sh, rb48, nullptr, nullptr);
            else        relay_run<2, 1>(r, l, sh, rb48, nullptr,
                                        edge + (size_t)(q - 1) * 400);
        } else {
            if (q == NBLK - 1) relay_run<1, 0>(r, l, sh, rb48, nullptr, nullptr);
            else               relay_run<1, 2>(r, l, sh, rb48,
                                               edge + (size_t)q * 400, nullptr);
        }
    } else {
        // -------- IO waves: feed W tiles + drain mu for relay r = w-2
        const int r = w - 2;
        const int rb48 = 96 * q + 48 * r;
        float f0[6], f1[6], f2[6], rA[6], rB[6];
        loadW6(Wb, rb48, 0, l, f0);
        loadW6(Wb, rb48, 1, l, f1);
        loadW6(Wb, rb48, 2, l, f2);
        loadW6(Wb, rb48, 3, l, rA);
        loadW6(Wb, rb48, 4, l, rB);
        writeWt6(&sh.wtile[0][r][0], f0, l);
        writeWt6(&sh.wtile[1][r][0], f1, l);
        writeWt6(&sh.wtile[2][r][0], f2, l);
        asm volatile("s_waitcnt lgkmcnt(0)" ::: "memory");
        if (l == 0) *(volatile int*)&sh.wready[r] = 3;

        for (int k = 0; k < 6; k += 2) {
            io_iter<false>(k,     r, l, Wb, rb48, mub, rA, sh);
            io_iter<false>(k + 1, r, l, Wb, rb48, mub, rB, sh);
        }
        for (int k = 6; k < 48; k += 2) {
            io_iter<true >(k,     r, l, Wb, rb48, mub, rA, sh);
            io_iter<true >(k + 1, r, l, Wb, rb48, mub, rB, sh);
        }
        for (int k = 48; k < TOT_CH; k += 2) {
            io_iter<false>(k,     r, l, Wb, rb48, mub, rA, sh);
            io_iter<false>(k + 1, r, l, Wb, rb48, mub, rB, sh);
        }
    }
}

// ---------------- pass 2: pi = exp(x + W - mu_ij) * mask ----------------
__global__ __launch_bounds__(256) void dtw_pi(const float* __restrict__ W,
        const float* __restrict__ mask, const float* __restrict__ mu,
        float* __restrict__ pi)
{
    const long long idx = ((long long)blockIdx.x * 256 + threadIdx.x) * 4;
    const int rr = (int)(idx / NB);          // b*NA + ii
    const int jj = (int)(idx - (long long)rr * NB);
    const int b  = rr / NA;
    const int ii = rr - b * NA;
    const float* m0 = mu + (size_t)b * MUP * MUP + (size_t)ii * MUP + jj;
    const float* m1 = m0 + MUP;
    const float d0 = m0[0], d1 = m0[1], d2 = m0[2], d3 = m0[3], d4 = m0[4];
    const float L0 = m1[0], L1 = m1[1], L2 = m1[2], L3 = m1[3], L4 = m1[4];
    const f4 wv = *(const f4*)(W + idx);
    const f4 mk = *(const f4*)(mask + idx);

    const float t0 = wv.x - L1, t1 = wv.y - L2, t2 = wv.z - L3, t3 = wv.w - L4;
    f4 o0, o1, o2;
    o0.x = exp2f((d1 + t0) * LOG2E) * mk.x;
    o0.y = exp2f((L0 + t0) * LOG2E) * mk.x;
    o0.z = exp2f((d0 + t0) * LOG2E) * mk.x;
    o0.w = exp2f((d2 + t1) * LOG2E) * mk.y;
    o1.x = exp2f((L1 + t1) * LOG2E) * mk.y;
    o1.y = exp2f((d1 + t1) * LOG2E) * mk.y;
    o1.z = exp2f((d3 + t2) * LOG2E) * mk.z;
    o1.w = exp2f((L2 + t2) * LOG2E) * mk.z;
    o2.x = exp2f((d2 + t2) * LOG2E) * mk.z;
    o2.y = exp2f((d4 + t3) * LOG2E) * mk.w;
    o2.z = exp2f((L3 + t3) * LOG2E) * mk.w;
    o2.w = exp2f((d3 + t3) * LOG2E) * mk.w;

    f4* po = (f4*)(pi + idx * 3);
    po[0] = o0; po[1] = o1; po[2] = o2;
}

extern "C" void kernel_launch(void* const* d_in, const int* in_sizes, int n_in,
                              void* d_out, int out_size, void* d_ws, size_t ws_size,
                              hipStream_t stream) {
    const float* W    = (const float*)d_in[0];
    const float* mask = (const float*)d_in[1];
    float* mu = (float*)d_out;
    float* pi = mu + (size_t)NBATCH * MUP * MUP;

    hipLaunchKernelGGL(dtw_mu, dim3(NBATCH * NBLK), dim3(256), 0, stream, W, mu);

    const int cells  = NBATCH * NA * NB;              // 9437184
    const int blocks = cells / (256 * 4);             // 9216
    hipLaunchKernelGGL(dtw_pi, dim3(blocks), dim3(256), 0, stream,
                       W, mask, mu, pi);
}